// Round 1
// baseline (166.477 us; speedup 1.0000x reference)
//
#include <hip/hip_runtime.h>
#include <hip/hip_bf16.h>

// MechanismGrabber: B=2,S=4096,D=128,M=64. Outputs: integrated [8192,128] f32, vp [8192] f32.
// Strategy: bf16 MFMA (16x16x32) for all GEMMs; victory via precomputed u_m = Wt[m]@Wv[m];
// selected = sum_m w[t,m]*(x@Wt[m]) + w_row@(bt+char), w = gates*scores*timing.

typedef __bf16 bf16_t;
typedef __bf16 bf16x8 __attribute__((ext_vector_type(8)));
typedef float  f32x4  __attribute__((ext_vector_type(4)));

// ws layout (bytes)
#define WS_WTT      0u          // bf16 [64][128 e][128 d] swizzled (Wt^T), 2 MB
#define WS_W1T      2097152u    // bf16 [256 out][256 in]
#define WS_W2T      2228224u    // bf16 [64 out][256 in]
#define WS_OT       2260992u    // bf16 [64 out][64 in]
#define WS_WG       2269184u    // bf16 [64][128]
#define WS_U        2285568u    // bf16 [64][128]
#define WS_CVEC     2301952u    // f32  [64]
#define WS_BCT      2302208u    // bf16 [128 e][64 m]  (bt+char)^T
#define WS_WIT      2318592u    // bf16 [128 out][256 in]
#define WS_W        2384128u    // f32  [8192][64]   combined weights
#define WS_SBIAS    4481280u    // f32  [8192][128]  w_row @ (bt+char)
#define WS_SEL      8675584u    // f32  [8192][128]  selected

#define VP_OFF 1048576

__device__ __forceinline__ f32x4 mfma16(bf16x8 a, bf16x8 b, f32x4 c) {
  return __builtin_amdgcn_mfma_f32_16x16x32_bf16(a, b, c, 0, 0, 0);
}

__device__ __forceinline__ void gld_lds16(const void* g, void* l) {
  __builtin_amdgcn_global_load_lds(
      (const __attribute__((address_space(1))) void*)g,
      (__attribute__((address_space(3))) void*)l, 16, 0, 0);
}

__device__ __forceinline__ float gelu_exact(float v) {
  return 0.5f * v * (1.0f + erff(v * 0.70710678118654752f));
}
__device__ __forceinline__ float sigmoidf_(float v) {
  return 1.0f / (1.0f + __expf(-v));
}

// ---------------------------------------------------------------- kernel P
// Pre-transposes / bf16-casts weights; computes u_m, c_m, bct.
__global__ __launch_bounds__(256) void kprep(
    const float* __restrict__ Wt, const float* __restrict__ bt,
    const float* __restrict__ ch, const float* __restrict__ Wg,
    const float* __restrict__ Wv, const float* __restrict__ bv,
    const float* __restrict__ O, const float* __restrict__ W1,
    const float* __restrict__ W2, const float* __restrict__ Wi,
    char* __restrict__ ws)
{
  const int bid = blockIdx.x, tid = threadIdx.x;
  if (bid < 64) {
    const int m = bid;
    const float* wtm = Wt + m * 16384;
    bf16_t* wtt = (bf16_t*)(ws + WS_WTT) + m * 16384;
    // Wt[m][d][e] -> Wtt[e][d] bf16, XOR-swizzled in 16B units: unit q=e*16+d/8 stored at q^(e&7).
    // Coalesced reads (contiguous e), scattered 2B writes (async stores, no stall).
    #pragma unroll
    for (int i = 0; i < 8; ++i) {
      int task = tid + i * 256;            // 2048 tasks: d x e-chunk
      int d = task >> 4, e0 = (task & 15) * 8;
      float vv[8];
      #pragma unroll
      for (int j = 0; j < 8; ++j) vv[j] = wtm[d * 128 + e0 + j];
      #pragma unroll
      for (int j = 0; j < 8; ++j) {
        int e = e0 + j;
        int q = e * 16 + (d >> 3);
        ((bf16_t*)((char*)wtt + ((q ^ (e & 7)) << 4)))[d & 7] = (bf16_t)vv[j];
      }
    }
    if (tid < 128) {  // u[m][d] = sum_e Wt[m][d][e]*Wv[m][e]
      const float* wvm = Wv + m * 128;
      float s = 0.f;
      for (int e = 0; e < 128; ++e) s += wtm[tid * 128 + e] * wvm[e];
      ((bf16_t*)(ws + WS_U))[m * 128 + tid] = (bf16_t)s;
    } else if (tid == 128) {  // c[m] = (bt+char)@Wv + bv
      const float* wvm = Wv + m * 128;
      float s = bv[m];
      for (int e = 0; e < 128; ++e) s += (bt[m * 128 + e] + ch[m * 128 + e]) * wvm[e];
      ((float*)(ws + WS_CVEC))[m] = s;
    }
  } else if (bid < 80) {  // W1t[c][k] = W1[k][c]
    int base = (bid - 64) * 256 + tid;    // 4096 tasks
    int k = base >> 4, c0 = (base & 15) * 16;
    bf16_t* o = (bf16_t*)(ws + WS_W1T);
    #pragma unroll
    for (int j = 0; j < 16; ++j) o[(c0 + j) * 256 + k] = (bf16_t)W1[k * 256 + c0 + j];
  } else if (bid < 82) {  // W2t[c][k] = W2[k][c]
    int base = (bid - 80) * 256 + tid;    // 512 tasks
    int k = base >> 1, c0 = (base & 1) * 32;
    bf16_t* o = (bf16_t*)(ws + WS_W2T);
    #pragma unroll
    for (int j = 0; j < 32; ++j) o[(c0 + j) * 256 + k] = (bf16_t)W2[k * 64 + c0 + j];
  } else if (bid == 82) { // Ot[c][k] = O[k][c]
    int k = tid >> 2, c0 = (tid & 3) * 16;
    bf16_t* o = (bf16_t*)(ws + WS_OT);
    #pragma unroll
    for (int j = 0; j < 16; ++j) o[(c0 + j) * 64 + k] = (bf16_t)O[k * 64 + c0 + j];
  } else if (bid == 83) { // Wg bf16 copy
    bf16_t* o = (bf16_t*)(ws + WS_WG);
    #pragma unroll
    for (int j = 0; j < 32; ++j) o[tid * 32 + j] = (bf16_t)Wg[tid * 32 + j];
  } else if (bid == 84) { // bct[e][m] = bt[m][e]+char[m][e]
    bf16_t* o = (bf16_t*)(ws + WS_BCT);
    #pragma unroll
    for (int i = 0; i < 4; ++i) {
      int task = tid + i * 256;           // 1024 tasks
      int m = task >> 4, e0 = (task & 15) * 8;
      #pragma unroll
      for (int j = 0; j < 8; ++j)
        o[(e0 + j) * 64 + m] = (bf16_t)(bt[m * 128 + e0 + j] + ch[m * 128 + e0 + j]);
    }
  } else {               // 85..88: Wit[c][k] = Wi[k][c]
    int base = (bid - 85) * 256 + tid;    // 1024 tasks
    int k = base >> 2, c0 = (base & 3) * 32;
    bf16_t* o = (bf16_t*)(ws + WS_WIT);
    #pragma unroll
    for (int j = 0; j < 32; ++j) o[(c0 + j) * 256 + k] = (bf16_t)Wi[k * 128 + c0 + j];
  }
}

// ---------------------------------------------------------------- kernel B
// Per 32-token tile: selector MLP -> softmax scores; timing, victory, gates;
// w = gates*scores*timing -> ws; sbias = w@ (bt+char) -> ws; vp -> out.
__global__ __launch_bounds__(256) void kselect(
    const float* __restrict__ x, const float* __restrict__ ctx,
    const float* __restrict__ b1, const float* __restrict__ b2,
    const float* __restrict__ bg,
    char* __restrict__ ws, float* __restrict__ out)
{
  __shared__ char sm[41472];
  bf16_t* hL      = (bf16_t*)sm;               // [32][256] bf16 swz, 16KB
  float*  logitsL = (float*)(sm + 16384);      // [32][64]
  float*  scoresL = (float*)(sm + 24576);      // [32][64]
  bf16_t* scbL    = (bf16_t*)(sm + 32768);     // [32][64] bf16 swz
  bf16_t* wbL     = (bf16_t*)(sm + 36864);     // [32][64] bf16 swz
  float*  vpL     = (float*)(sm + 40960);      // [32][4]

  const int tid = threadIdx.x;
  const int lane = tid & 63, wid = tid >> 6;
  const int tb = blockIdx.x * 32;
  const int lr = lane & 15;
  const int lk = (lane >> 4) * 8;
  const int lj4 = (lane >> 4) * 4;

  const bf16_t* W1t = (const bf16_t*)(ws + WS_W1T);
  const bf16_t* W2t = (const bf16_t*)(ws + WS_W2T);
  const bf16_t* Ot  = (const bf16_t*)(ws + WS_OT);
  const bf16_t* Wgb = (const bf16_t*)(ws + WS_WG);
  const bf16_t* Ub  = (const bf16_t*)(ws + WS_U);
  const float*  cv  = (const float*)(ws + WS_CVEC);
  const bf16_t* bct = (const bf16_t*)(ws + WS_BCT);
  float* wOut  = (float*)(ws + WS_W);
  float* sbOut = (float*)(ws + WS_SBIAS);

  // A-frags of sel_in = [x | ctx]: [rg][ks], k = ks*32 + lk + j
  bf16x8 aSel[2][8];
  #pragma unroll
  for (int rg = 0; rg < 2; ++rg) {
    int t = tb + rg * 16 + lr;
    #pragma unroll
    for (int ks = 0; ks < 8; ++ks) {
      const float* src = (ks < 4) ? (x + t * 128 + ks * 32 + lk)
                                  : (ctx + t * 128 + (ks - 4) * 32 + lk);
      bf16x8 a;
      #pragma unroll
      for (int j = 0; j < 8; ++j) a[j] = (bf16_t)src[j];
      aSel[rg][ks] = a;
    }
  }

  // GEMM1: [32,256]@W1 -> gelu -> hL (bf16 swz)
  #pragma unroll
  for (int cg = 0; cg < 4; ++cg) {
    int c = wid * 64 + cg * 16 + lr;
    f32x4 a0 = {0.f,0.f,0.f,0.f}, a1 = {0.f,0.f,0.f,0.f};
    #pragma unroll
    for (int ks = 0; ks < 8; ++ks) {
      bf16x8 b = *(const bf16x8*)(W1t + c * 256 + ks * 32 + lk);
      a0 = mfma16(aSel[0][ks], b, a0);
      a1 = mfma16(aSel[1][ks], b, a1);
    }
    float bb = b1[c];
    #pragma unroll
    for (int j = 0; j < 4; ++j) {
      int r0 = lj4 + j, r1 = 16 + lj4 + j;
      float v0 = gelu_exact(a0[j] + bb);
      float v1 = gelu_exact(a1[j] + bb);
      *(bf16_t*)((char*)hL + ((r0 * 512 + c * 2) ^ ((r0 & 7) << 4))) = (bf16_t)v0;
      *(bf16_t*)((char*)hL + ((r1 * 512 + c * 2) ^ ((r1 & 7) << 4))) = (bf16_t)v1;
    }
  }
  __syncthreads();

  // GEMM2: h@W2 + b2 -> logits
  {
    int c = wid * 16 + lr;
    f32x4 l0 = {0.f,0.f,0.f,0.f}, l1 = {0.f,0.f,0.f,0.f};
    #pragma unroll
    for (int ks = 0; ks < 8; ++ks) {
      int k0 = ks * 32 + lk;
      bf16x8 a0 = *(const bf16x8*)((char*)hL + ((lr * 512 + k0 * 2) ^ ((lr & 7) << 4)));
      bf16x8 a1 = *(const bf16x8*)((char*)hL + (((16 + lr) * 512 + k0 * 2) ^ ((lr & 7) << 4)));
      bf16x8 b  = *(const bf16x8*)(W2t + c * 256 + k0);
      l0 = mfma16(a0, b, l0);
      l1 = mfma16(a1, b, l1);
    }
    float bb = b2[c];
    #pragma unroll
    for (int j = 0; j < 4; ++j) {
      logitsL[(lj4 + j) * 64 + c] = l0[j] + bb;
      logitsL[(16 + lj4 + j) * 64 + c] = l1[j] + bb;
    }
  }
  __syncthreads();

  // softmax over 64 mechs: 8 threads per row
  {
    int row = tid >> 3, i = tid & 7;
    float v[8];
    #pragma unroll
    for (int j = 0; j < 8; ++j) v[j] = logitsL[row * 64 + i * 8 + j];
    float mx = v[0];
    #pragma unroll
    for (int j = 1; j < 8; ++j) mx = fmaxf(mx, v[j]);
    mx = fmaxf(mx, __shfl_xor(mx, 1));
    mx = fmaxf(mx, __shfl_xor(mx, 2));
    mx = fmaxf(mx, __shfl_xor(mx, 4));
    float sum = 0.f;
    #pragma unroll
    for (int j = 0; j < 8; ++j) { v[j] = __expf(v[j] - mx); sum += v[j]; }
    sum += __shfl_xor(sum, 1);
    sum += __shfl_xor(sum, 2);
    sum += __shfl_xor(sum, 4);
    float inv = 1.0f / sum;
    #pragma unroll
    for (int j = 0; j < 8; ++j) {
      float s = v[j] * inv;
      int cc = i * 8 + j;
      scoresL[row * 64 + cc] = s;
      *(bf16_t*)((char*)scbL + ((row * 128 + cc * 2) ^ ((row & 7) << 4))) = (bf16_t)s;
    }
  }
  __syncthreads();

  const int c = wid * 16 + lr;  // mechanism column for this wave
  // gates = 1 + tanh(scores @ O)
  f32x4 g0 = {0.f,0.f,0.f,0.f}, g1 = {0.f,0.f,0.f,0.f};
  #pragma unroll
  for (int ks = 0; ks < 2; ++ks) {
    int k0 = ks * 32 + lk;
    bf16x8 a0 = *(const bf16x8*)((char*)scbL + ((lr * 128 + k0 * 2) ^ ((lr & 7) << 4)));
    bf16x8 a1 = *(const bf16x8*)((char*)scbL + (((16 + lr) * 128 + k0 * 2) ^ ((lr & 7) << 4)));
    bf16x8 b  = *(const bf16x8*)(Ot + c * 64 + k0);
    g0 = mfma16(a0, b, g0);
    g1 = mfma16(a1, b, g1);
  }
  // timing = sigmoid(x@Wg + bg); victory = sigmoid(x@u + cvec)
  f32x4 t0 = {0.f,0.f,0.f,0.f}, t1 = {0.f,0.f,0.f,0.f};
  f32x4 v0 = {0.f,0.f,0.f,0.f}, v1 = {0.f,0.f,0.f,0.f};
  #pragma unroll
  for (int ks = 0; ks < 4; ++ks) {
    bf16x8 bT = *(const bf16x8*)(Wgb + c * 128 + ks * 32 + lk);
    bf16x8 bV = *(const bf16x8*)(Ub  + c * 128 + ks * 32 + lk);
    t0 = mfma16(aSel[0][ks], bT, t0);
    t1 = mfma16(aSel[1][ks], bT, t1);
    v0 = mfma16(aSel[0][ks], bV, v0);
    v1 = mfma16(aSel[1][ks], bV, v1);
  }
  {
    float bgc = bg[c], cvc = cv[c];
    #pragma unroll
    for (int j = 0; j < 4; ++j) {
      { // rg 0
        int r = lj4 + j;
        float gate = 1.0f + tanhf(g0[j]);
        float tim  = sigmoidf_(t0[j] + bgc);
        float vic  = sigmoidf_(v0[j] + cvc);
        float sc   = scoresL[r * 64 + c];
        float w    = gate * sc * tim;
        wOut[(tb + r) * 64 + c] = w;
        *(bf16_t*)((char*)wbL + ((r * 128 + c * 2) ^ ((r & 7) << 4))) = (bf16_t)w;
        float pv = vic * sc;
        pv += __shfl_xor(pv, 1); pv += __shfl_xor(pv, 2);
        pv += __shfl_xor(pv, 4); pv += __shfl_xor(pv, 8);
        if (lr == 0) vpL[r * 4 + wid] = pv;
      }
      { // rg 1
        int r = 16 + lj4 + j;
        float gate = 1.0f + tanhf(g1[j]);
        float tim  = sigmoidf_(t1[j] + bgc);
        float vic  = sigmoidf_(v1[j] + cvc);
        float sc   = scoresL[r * 64 + c];
        float w    = gate * sc * tim;
        wOut[(tb + r) * 64 + c] = w;
        *(bf16_t*)((char*)wbL + ((r * 128 + c * 2) ^ ((r & 7) << 4))) = (bf16_t)w;
        float pv = vic * sc;
        pv += __shfl_xor(pv, 1); pv += __shfl_xor(pv, 2);
        pv += __shfl_xor(pv, 4); pv += __shfl_xor(pv, 8);
        if (lr == 0) vpL[r * 4 + wid] = pv;
      }
    }
  }
  __syncthreads();

  // sbias = w @ (bt+char): [32,64]@[64,128]
  {
    f32x4 s00 = {0.f,0.f,0.f,0.f}, s01 = {0.f,0.f,0.f,0.f};
    f32x4 s10 = {0.f,0.f,0.f,0.f}, s11 = {0.f,0.f,0.f,0.f};
    int c0 = wid * 32 + lr, c1 = wid * 32 + 16 + lr;
    #pragma unroll
    for (int ks = 0; ks < 2; ++ks) {
      int k0 = ks * 32 + lk;
      bf16x8 a0 = *(const bf16x8*)((char*)wbL + ((lr * 128 + k0 * 2) ^ ((lr & 7) << 4)));
      bf16x8 a1 = *(const bf16x8*)((char*)wbL + (((16 + lr) * 128 + k0 * 2) ^ ((lr & 7) << 4)));
      bf16x8 bb0 = *(const bf16x8*)(bct + c0 * 64 + k0);
      bf16x8 bb1 = *(const bf16x8*)(bct + c1 * 64 + k0);
      s00 = mfma16(a0, bb0, s00); s01 = mfma16(a0, bb1, s01);
      s10 = mfma16(a1, bb0, s10); s11 = mfma16(a1, bb1, s11);
    }
    #pragma unroll
    for (int j = 0; j < 4; ++j) {
      sbOut[(tb + lj4 + j) * 128 + c0] = s00[j];
      sbOut[(tb + lj4 + j) * 128 + c1] = s01[j];
      sbOut[(tb + 16 + lj4 + j) * 128 + c0] = s10[j];
      sbOut[(tb + 16 + lj4 + j) * 128 + c1] = s11[j];
    }
  }
  // vp finalize (vpL written before the barrier above)
  if (tid < 32) {
    float s = vpL[tid * 4 + 0] + vpL[tid * 4 + 1] + vpL[tid * 4 + 2] + vpL[tid * 4 + 3];
    out[VP_OFF + tb + tid] = s;
  }
}

// ---------------------------------------------------------------- kernel C
// selected[t,e] = sum_m w[t,m]*(x@Wt[m])[t,e] + sbias[t,e]
// Tile: 64 tokens x 64 e-cols; grid 256 = 128 tokTiles x 2 colHalves; m-loop, dbuf LDS staging.
__global__ __launch_bounds__(256) void kmech(
    const float* __restrict__ x, char* __restrict__ ws)
{
  __shared__ char sm[49152];  // buf0 16K @0, buf1 16K @16384, wL 16K @32768
  const int tid = threadIdx.x;
  const int lane = tid & 63, wid = tid >> 6;
  const int tb = (blockIdx.x >> 1) * 64;
  const int eh = blockIdx.x & 1;
  const int lr = lane & 15;
  const int lk = (lane >> 4) * 8;
  const int lj4 = (lane >> 4) * 4;
  const int wrow = (wid & 1) * 32;   // wave token offset in tile
  const int wcol = (wid >> 1) * 32;  // wave col offset in 64-col half

  const char* wttAll = (const char*)(ws + WS_WTT);
  const float* wIn  = (const float*)(ws + WS_W);
  const float* sbIn = (const float*)(ws + WS_SBIAS);
  float* selOut = (float*)(ws + WS_SEL);
  float* wL = (float*)(sm + 32768);

  // stage m=0 (overlaps with everything below; first barrier drains vmcnt)
  {
    const char* g = wttAll + 0 * 32768 + eh * 16384;
    char* l = sm + 0;
    #pragma unroll
    for (int r = 0; r < 4; ++r)
      gld_lds16(g + r * 4096 + tid * 16, l + r * 4096 + wid * 1024);
  }
  // stage w tile [64 tok][64 m] f32
  {
    const float4* s = (const float4*)(wIn + tb * 64);
    float4* d = (float4*)wL;
    #pragma unroll
    for (int i = 0; i < 4; ++i) d[tid + i * 256] = s[tid + i * 256];
  }
  // x A-frags for this wave's 32 tokens
  bf16x8 aX[2][4];
  #pragma unroll
  for (int rg = 0; rg < 2; ++rg) {
    const float* xr = x + (tb + wrow + rg * 16 + lr) * 128;
    #pragma unroll
    for (int ks = 0; ks < 4; ++ks) {
      bf16x8 a;
      #pragma unroll
      for (int j = 0; j < 8; ++j) a[j] = (bf16_t)xr[ks * 32 + lk + j];
      aX[rg][ks] = a;
    }
  }
  // acc init from sbias
  f32x4 acc[2][2];
  #pragma unroll
  for (int rg = 0; rg < 2; ++rg)
    #pragma unroll
    for (int cg = 0; cg < 2; ++cg) {
      f32x4 a;
      #pragma unroll
      for (int j = 0; j < 4; ++j)
        a[j] = sbIn[(tb + wrow + rg * 16 + lj4 + j) * 128 + eh * 64 + wcol + cg * 16 + lr];
      acc[rg][cg] = a;
    }
  __syncthreads();  // buf0 staged + wL visible

  const int e0 = wcol + lr, e1 = wcol + 16 + lr;  // local e within half
  for (int m = 0; m < 64; ++m) {
    const char* cur = sm + (m & 1) * 16384;
    if (m < 63) {  // stage m+1 into other buffer
      const char* g = wttAll + (m + 1) * 32768 + eh * 16384;
      char* l = sm + ((m + 1) & 1) * 16384;
      #pragma unroll
      for (int r = 0; r < 4; ++r)
        gld_lds16(g + r * 4096 + tid * 16, l + r * 4096 + wid * 1024);
    }
    f32x4 y00 = {0.f,0.f,0.f,0.f}, y01 = {0.f,0.f,0.f,0.f};
    f32x4 y10 = {0.f,0.f,0.f,0.f}, y11 = {0.f,0.f,0.f,0.f};
    #pragma unroll
    for (int ks = 0; ks < 4; ++ks) {
      int u = (ks * 32 + lk) >> 3;
      bf16x8 b0 = *(const bf16x8*)(cur + (((e0 * 16 + u) ^ (e0 & 7)) << 4));
      bf16x8 b1 = *(const bf16x8*)(cur + (((e1 * 16 + u) ^ (e1 & 7)) << 4));
      y00 = mfma16(aX[0][ks], b0, y00);
      y01 = mfma16(aX[0][ks], b1, y01);
      y10 = mfma16(aX[1][ks], b0, y10);
      y11 = mfma16(aX[1][ks], b1, y11);
    }
    #pragma unroll
    for (int j = 0; j < 4; ++j) {
      float w0 = wL[(wrow + lj4 + j) * 64 + m];
      float w1 = wL[(wrow + 16 + lj4 + j) * 64 + m];
      acc[0][0][j] += w0 * y00[j];
      acc[0][1][j] += w0 * y01[j];
      acc[1][0][j] += w1 * y10[j];
      acc[1][1][j] += w1 * y11[j];
    }
    __syncthreads();
  }
  // write selected
  #pragma unroll
  for (int rg = 0; rg < 2; ++rg)
    #pragma unroll
    for (int cg = 0; cg < 2; ++cg)
      #pragma unroll
      for (int j = 0; j < 4; ++j)
        selOut[(tb + wrow + rg * 16 + lj4 + j) * 128 + eh * 64 + wcol + cg * 16 + lr]
            = acc[rg][cg][j];
}

// ---------------------------------------------------------------- kernel D
// integrated = [x | selected] @ Wi + bi
__global__ __launch_bounds__(256) void kinteg(
    const float* __restrict__ x, const float* __restrict__ bi,
    const char* __restrict__ ws, float* __restrict__ out)
{
  const int tid = threadIdx.x;
  const int lane = tid & 63, wid = tid >> 6;
  const int tb = blockIdx.x * 32;
  const int lr = lane & 15, lk = (lane >> 4) * 8, lj4 = (lane >> 4) * 4;
  const bf16_t* Wit = (const bf16_t*)(ws + WS_WIT);
  const float* sel = (const float*)(ws + WS_SEL);

  bf16x8 aF[2][8];
  #pragma unroll
  for (int rg = 0; rg < 2; ++rg) {
    int t = tb + rg * 16 + lr;
    #pragma unroll
    for (int ks = 0; ks < 8; ++ks) {
      const float* src = (ks < 4) ? (x + t * 128 + ks * 32 + lk)
                                  : (sel + t * 128 + (ks - 4) * 32 + lk);
      bf16x8 a;
      #pragma unroll
      for (int j = 0; j < 8; ++j) a[j] = (bf16_t)src[j];
      aF[rg][ks] = a;
    }
  }
  #pragma unroll
  for (int cg = 0; cg < 2; ++cg) {
    int c = wid * 32 + cg * 16 + lr;
    f32x4 a0 = {0.f,0.f,0.f,0.f}, a1 = {0.f,0.f,0.f,0.f};
    #pragma unroll
    for (int ks = 0; ks < 8; ++ks) {
      bf16x8 b = *(const bf16x8*)(Wit + c * 256 + ks * 32 + lk);
      a0 = mfma16(aF[0][ks], b, a0);
      a1 = mfma16(aF[1][ks], b, a1);
    }
    float bb = bi[c];
    #pragma unroll
    for (int j = 0; j < 4; ++j) {
      out[(tb + lj4 + j) * 128 + c] = a0[j] + bb;
      out[(tb + 16 + lj4 + j) * 128 + c] = a1[j] + bb;
    }
  }
}

// ---------------------------------------------------------------- launch
extern "C" void kernel_launch(void* const* d_in, const int* in_sizes, int n_in,
                              void* d_out, int out_size, void* d_ws, size_t ws_size,
                              hipStream_t stream)
{
  (void)in_sizes; (void)n_in; (void)out_size; (void)ws_size;
  const float* x   = (const float*)d_in[0];
  const float* ctx = (const float*)d_in[1];
  const float* Wt  = (const float*)d_in[2];
  const float* bt  = (const float*)d_in[3];
  const float* ch  = (const float*)d_in[4];
  const float* Wg  = (const float*)d_in[5];
  const float* bg  = (const float*)d_in[6];
  const float* Wv  = (const float*)d_in[7];
  const float* bv  = (const float*)d_in[8];
  const float* O   = (const float*)d_in[9];
  const float* W1  = (const float*)d_in[10];
  const float* b1  = (const float*)d_in[11];
  const float* W2  = (const float*)d_in[12];
  const float* b2  = (const float*)d_in[13];
  const float* Wi  = (const float*)d_in[14];
  const float* bi  = (const float*)d_in[15];
  float* out = (float*)d_out;
  char* ws = (char*)d_ws;

  kprep<<<89, 256, 0, stream>>>(Wt, bt, ch, Wg, Wv, bv, O, W1, W2, Wi, ws);
  kselect<<<256, 256, 0, stream>>>(x, ctx, b1, b2, bg, ws, out);
  kmech<<<256, 256, 0, stream>>>(x, ws);
  kinteg<<<256, 256, 0, stream>>>(x, bi, ws, out);
}

// Round 3
// 143.759 us; speedup vs baseline: 1.1580x; 1.1580x over previous
//
#include <hip/hip_runtime.h>
#include <hip/hip_bf16.h>

// MechanismGrabber: B=2,S=4096,D=128,M=64. Outputs: integrated [8192,128] f32, vp [8192] f32.
// bf16 MFMA everywhere; victory via u_m = Wt[m]@Wv[m]; selected = sum_m w[t,m]*(x@Wt[m]) + w@ (bt+char).
// R2: kmech = barrier-free, B-frags direct from L2 (frag-major Wt^T layout), depth-3 reg pipeline.

typedef __bf16 bf16_t;
typedef __bf16 bf16x8 __attribute__((ext_vector_type(8)));
typedef float  f32x4  __attribute__((ext_vector_type(4)));

// ws layout (bytes)
#define WS_WTT      0u          // bf16 [m][ks(4)][e(128)][g(4)][j(8)]  (frag-major Wt^T), 2 MB
#define WS_W1T      2097152u    // bf16 [256 out][256 in]
#define WS_W2T      2228224u    // bf16 [64 out][256 in]
#define WS_OT       2260992u    // bf16 [64 out][64 in]
#define WS_WG       2269184u    // bf16 [64][128]
#define WS_U        2285568u    // bf16 [64][128]
#define WS_CVEC     2301952u    // f32  [64]
#define WS_BCT      2302208u    // bf16 [128 e][64 m]  (bt+char)^T
#define WS_WIT      2318592u    // bf16 [128 out][256 in]
#define WS_W        2384128u    // f32  [8192][64]   combined weights w = gate*score*timing
#define WS_SBIAS    4481280u    // f32  [8192][128]  w_row @ (bt+char)
#define WS_SEL      8675584u    // f32  [8192][128]  selected

#define VP_OFF 1048576

__device__ __forceinline__ f32x4 mfma16(bf16x8 a, bf16x8 b, f32x4 c) {
  return __builtin_amdgcn_mfma_f32_16x16x32_bf16(a, b, c, 0, 0, 0);
}

__device__ __forceinline__ float gelu_exact(float v) {
  return 0.5f * v * (1.0f + erff(v * 0.70710678118654752f));
}
__device__ __forceinline__ float sigmoidf_(float v) {
  return 1.0f / (1.0f + __expf(-v));
}

__device__ __forceinline__ bf16x8 cvt8(float4 v0, float4 v1) {
  bf16x8 a;
  a[0] = (bf16_t)v0.x; a[1] = (bf16_t)v0.y; a[2] = (bf16_t)v0.z; a[3] = (bf16_t)v0.w;
  a[4] = (bf16_t)v1.x; a[5] = (bf16_t)v1.y; a[6] = (bf16_t)v1.z; a[7] = (bf16_t)v1.w;
  return a;
}

// ---------------------------------------------------------------- kernel P
__global__ __launch_bounds__(256) void kprep(
    const float* __restrict__ Wt, const float* __restrict__ bt,
    const float* __restrict__ ch, const float* __restrict__ Wg,
    const float* __restrict__ Wv, const float* __restrict__ bv,
    const float* __restrict__ O, const float* __restrict__ W1,
    const float* __restrict__ W2, const float* __restrict__ Wi,
    char* __restrict__ ws)
{
  const int bid = blockIdx.x, tid = threadIdx.x;
  if (bid < 128) {
    // Wt[m][d][e] -> Wtt[m][ks][e][g][j] bf16 (d = ks*32+g*8+j); 2 blocks per m.
    const int m = bid >> 1, half = bid & 1;
    const float* wtm = Wt + m * 16384;
    bf16_t* wtt = (bf16_t*)(ws + WS_WTT) + m * 16384;
    const int ks = half * 2 + (tid >> 7), e = tid & 127;
    bf16_t tmp[32];
    #pragma unroll
    for (int dd = 0; dd < 32; ++dd)
      tmp[dd] = (bf16_t)wtm[(ks * 32 + dd) * 128 + e];  // coalesced across lanes (e)
    bf16_t* dst = wtt + ks * 4096 + e * 32;             // 64B contiguous per thread
    #pragma unroll
    for (int g = 0; g < 4; ++g)
      *(bf16x8*)(dst + g * 8) = *(const bf16x8*)(tmp + g * 8);
    if (half == 0) {
      if (tid < 128) {  // u[m][d] = sum_e Wt[m][d][e]*Wv[m][e]
        const float* wvm = Wv + m * 128;
        float s = 0.f;
        for (int e2 = 0; e2 < 128; ++e2) s += wtm[tid * 128 + e2] * wvm[e2];
        ((bf16_t*)(ws + WS_U))[m * 128 + tid] = (bf16_t)s;
      } else if (tid == 128) {  // c[m] = (bt+char)@Wv + bv
        const float* wvm = Wv + m * 128;
        float s = bv[m];
        for (int e2 = 0; e2 < 128; ++e2) s += (bt[m * 128 + e2] + ch[m * 128 + e2]) * wvm[e2];
        ((float*)(ws + WS_CVEC))[m] = s;
      }
    }
  } else if (bid < 144) {  // W1t[c][k] = W1[k][c]
    int base = (bid - 128) * 256 + tid;
    int k = base >> 4, c0 = (base & 15) * 16;
    bf16_t* o = (bf16_t*)(ws + WS_W1T);
    #pragma unroll
    for (int j = 0; j < 16; ++j) o[(c0 + j) * 256 + k] = (bf16_t)W1[k * 256 + c0 + j];
  } else if (bid < 146) {  // W2t[c][k] = W2[k][c]
    int base = (bid - 144) * 256 + tid;
    int k = base >> 1, c0 = (base & 1) * 32;
    bf16_t* o = (bf16_t*)(ws + WS_W2T);
    #pragma unroll
    for (int j = 0; j < 32; ++j) o[(c0 + j) * 256 + k] = (bf16_t)W2[k * 64 + c0 + j];
  } else if (bid == 146) { // Ot[c][k] = O[k][c]
    int k = tid >> 2, c0 = (tid & 3) * 16;
    bf16_t* o = (bf16_t*)(ws + WS_OT);
    #pragma unroll
    for (int j = 0; j < 16; ++j) o[(c0 + j) * 64 + k] = (bf16_t)O[k * 64 + c0 + j];
  } else if (bid == 147) { // Wg bf16 copy
    bf16_t* o = (bf16_t*)(ws + WS_WG);
    #pragma unroll
    for (int j = 0; j < 32; ++j) o[tid * 32 + j] = (bf16_t)Wg[tid * 32 + j];
  } else if (bid == 148) { // bct[e][m] = bt[m][e]+char[m][e]
    bf16_t* o = (bf16_t*)(ws + WS_BCT);
    #pragma unroll
    for (int i = 0; i < 4; ++i) {
      int task = tid + i * 256;
      int m = task >> 4, e0 = (task & 15) * 8;
      #pragma unroll
      for (int j = 0; j < 8; ++j)
        o[(e0 + j) * 64 + m] = (bf16_t)(bt[m * 128 + e0 + j] + ch[m * 128 + e0 + j]);
    }
  } else {               // 149..152: Wit[c][k] = Wi[k][c]
    int base = (bid - 149) * 256 + tid;
    int k = base >> 2, c0 = (base & 3) * 32;
    bf16_t* o = (bf16_t*)(ws + WS_WIT);
    #pragma unroll
    for (int j = 0; j < 32; ++j) o[(c0 + j) * 256 + k] = (bf16_t)Wi[k * 128 + c0 + j];
  }
}

// ---------------------------------------------------------------- kernel B
__global__ __launch_bounds__(256) void kselect(
    const float* __restrict__ x, const float* __restrict__ ctx,
    const float* __restrict__ b1, const float* __restrict__ b2,
    const float* __restrict__ bg,
    char* __restrict__ ws, float* __restrict__ out)
{
  __shared__ char sm[41472];
  bf16_t* hL      = (bf16_t*)sm;               // [32][256] bf16 swz
  float*  logitsL = (float*)(sm + 16384);      // [32][64]
  float*  scoresL = (float*)(sm + 24576);      // [32][64]
  bf16_t* scbL    = (bf16_t*)(sm + 32768);     // [32][64] bf16 swz
  bf16_t* wbL     = (bf16_t*)(sm + 36864);     // [32][64] bf16 swz
  float*  vpL     = (float*)(sm + 40960);      // [32][4]

  const int tid = threadIdx.x;
  const int lane = tid & 63, wid = tid >> 6;
  const int tb = blockIdx.x * 32;
  const int lr = lane & 15;
  const int lk = (lane >> 4) * 8;
  const int lj4 = (lane >> 4) * 4;

  const bf16_t* W1t = (const bf16_t*)(ws + WS_W1T);
  const bf16_t* W2t = (const bf16_t*)(ws + WS_W2T);
  const bf16_t* Ot  = (const bf16_t*)(ws + WS_OT);
  const bf16_t* Wgb = (const bf16_t*)(ws + WS_WG);
  const bf16_t* Ub  = (const bf16_t*)(ws + WS_U);
  const float*  cv  = (const float*)(ws + WS_CVEC);
  const bf16_t* bct = (const bf16_t*)(ws + WS_BCT);
  float* wOut  = (float*)(ws + WS_W);
  float* sbOut = (float*)(ws + WS_SBIAS);

  bf16x8 aSel[2][8];
  #pragma unroll
  for (int rg = 0; rg < 2; ++rg) {
    int t = tb + rg * 16 + lr;
    #pragma unroll
    for (int ks = 0; ks < 8; ++ks) {
      const float* src = (ks < 4) ? (x + t * 128 + ks * 32 + lk)
                                  : (ctx + t * 128 + (ks - 4) * 32 + lk);
      aSel[rg][ks] = cvt8(*(const float4*)src, *(const float4*)(src + 4));
    }
  }

  // GEMM1: [32,256]@W1 -> gelu -> hL
  #pragma unroll
  for (int cg = 0; cg < 4; ++cg) {
    int c = wid * 64 + cg * 16 + lr;
    f32x4 a0 = {0.f,0.f,0.f,0.f}, a1 = {0.f,0.f,0.f,0.f};
    #pragma unroll
    for (int ks = 0; ks < 8; ++ks) {
      bf16x8 b = *(const bf16x8*)(W1t + c * 256 + ks * 32 + lk);
      a0 = mfma16(aSel[0][ks], b, a0);
      a1 = mfma16(aSel[1][ks], b, a1);
    }
    float bb = b1[c];
    #pragma unroll
    for (int j = 0; j < 4; ++j) {
      int r0 = lj4 + j, r1 = 16 + lj4 + j;
      float v0 = gelu_exact(a0[j] + bb);
      float v1 = gelu_exact(a1[j] + bb);
      *(bf16_t*)((char*)hL + ((r0 * 512 + c * 2) ^ ((r0 & 7) << 4))) = (bf16_t)v0;
      *(bf16_t*)((char*)hL + ((r1 * 512 + c * 2) ^ ((r1 & 7) << 4))) = (bf16_t)v1;
    }
  }
  __syncthreads();

  // GEMM2: h@W2 + b2 -> logits
  {
    int c = wid * 16 + lr;
    f32x4 l0 = {0.f,0.f,0.f,0.f}, l1 = {0.f,0.f,0.f,0.f};
    #pragma unroll
    for (int ks = 0; ks < 8; ++ks) {
      int k0 = ks * 32 + lk;
      bf16x8 a0 = *(const bf16x8*)((char*)hL + ((lr * 512 + k0 * 2) ^ ((lr & 7) << 4)));
      bf16x8 a1 = *(const bf16x8*)((char*)hL + (((16 + lr) * 512 + k0 * 2) ^ ((lr & 7) << 4)));
      bf16x8 b  = *(const bf16x8*)(W2t + c * 256 + k0);
      l0 = mfma16(a0, b, l0);
      l1 = mfma16(a1, b, l1);
    }
    float bb = b2[c];
    #pragma unroll
    for (int j = 0; j < 4; ++j) {
      logitsL[(lj4 + j) * 64 + c] = l0[j] + bb;
      logitsL[(16 + lj4 + j) * 64 + c] = l1[j] + bb;
    }
  }
  __syncthreads();

  // softmax over 64 mechs
  {
    int row = tid >> 3, i = tid & 7;
    float v[8];
    #pragma unroll
    for (int j = 0; j < 8; ++j) v[j] = logitsL[row * 64 + i * 8 + j];
    float mx = v[0];
    #pragma unroll
    for (int j = 1; j < 8; ++j) mx = fmaxf(mx, v[j]);
    mx = fmaxf(mx, __shfl_xor(mx, 1));
    mx = fmaxf(mx, __shfl_xor(mx, 2));
    mx = fmaxf(mx, __shfl_xor(mx, 4));
    float sum = 0.f;
    #pragma unroll
    for (int j = 0; j < 8; ++j) { v[j] = __expf(v[j] - mx); sum += v[j]; }
    sum += __shfl_xor(sum, 1);
    sum += __shfl_xor(sum, 2);
    sum += __shfl_xor(sum, 4);
    float inv = 1.0f / sum;
    #pragma unroll
    for (int j = 0; j < 8; ++j) {
      float s = v[j] * inv;
      int cc = i * 8 + j;
      scoresL[row * 64 + cc] = s;
      *(bf16_t*)((char*)scbL + ((row * 128 + cc * 2) ^ ((row & 7) << 4))) = (bf16_t)s;
    }
  }
  __syncthreads();

  const int c = wid * 16 + lr;
  f32x4 g0 = {0.f,0.f,0.f,0.f}, g1 = {0.f,0.f,0.f,0.f};
  #pragma unroll
  for (int ks = 0; ks < 2; ++ks) {
    int k0 = ks * 32 + lk;
    bf16x8 a0 = *(const bf16x8*)((char*)scbL + ((lr * 128 + k0 * 2) ^ ((lr & 7) << 4)));
    bf16x8 a1 = *(const bf16x8*)((char*)scbL + (((16 + lr) * 128 + k0 * 2) ^ ((lr & 7) << 4)));
    bf16x8 b  = *(const bf16x8*)(Ot + c * 64 + k0);
    g0 = mfma16(a0, b, g0);
    g1 = mfma16(a1, b, g1);
  }
  f32x4 t0 = {0.f,0.f,0.f,0.f}, t1 = {0.f,0.f,0.f,0.f};
  f32x4 v0 = {0.f,0.f,0.f,0.f}, v1 = {0.f,0.f,0.f,0.f};
  #pragma unroll
  for (int ks = 0; ks < 4; ++ks) {
    bf16x8 bT = *(const bf16x8*)(Wgb + c * 128 + ks * 32 + lk);
    bf16x8 bV = *(const bf16x8*)(Ub  + c * 128 + ks * 32 + lk);
    t0 = mfma16(aSel[0][ks], bT, t0);
    t1 = mfma16(aSel[1][ks], bT, t1);
    v0 = mfma16(aSel[0][ks], bV, v0);
    v1 = mfma16(aSel[1][ks], bV, v1);
  }
  {
    float bgc = bg[c], cvc = cv[c];
    #pragma unroll
    for (int j = 0; j < 4; ++j) {
      {
        int r = lj4 + j;
        float gate = 1.0f + tanhf(g0[j]);
        float tim  = sigmoidf_(t0[j] + bgc);
        float vic  = sigmoidf_(v0[j] + cvc);
        float sc   = scoresL[r * 64 + c];
        float w    = gate * sc * tim;
        wOut[(tb + r) * 64 + c] = w;
        *(bf16_t*)((char*)wbL + ((r * 128 + c * 2) ^ ((r & 7) << 4))) = (bf16_t)w;
        float pv = vic * sc;
        pv += __shfl_xor(pv, 1); pv += __shfl_xor(pv, 2);
        pv += __shfl_xor(pv, 4); pv += __shfl_xor(pv, 8);
        if (lr == 0) vpL[r * 4 + wid] = pv;
      }
      {
        int r = 16 + lj4 + j;
        float gate = 1.0f + tanhf(g1[j]);
        float tim  = sigmoidf_(t1[j] + bgc);
        float vic  = sigmoidf_(v1[j] + cvc);
        float sc   = scoresL[r * 64 + c];
        float w    = gate * sc * tim;
        wOut[(tb + r) * 64 + c] = w;
        *(bf16_t*)((char*)wbL + ((r * 128 + c * 2) ^ ((r & 7) << 4))) = (bf16_t)w;
        float pv = vic * sc;
        pv += __shfl_xor(pv, 1); pv += __shfl_xor(pv, 2);
        pv += __shfl_xor(pv, 4); pv += __shfl_xor(pv, 8);
        if (lr == 0) vpL[r * 4 + wid] = pv;
      }
    }
  }
  __syncthreads();

  // sbias = w @ (bt+char)
  {
    f32x4 s00 = {0.f,0.f,0.f,0.f}, s01 = {0.f,0.f,0.f,0.f};
    f32x4 s10 = {0.f,0.f,0.f,0.f}, s11 = {0.f,0.f,0.f,0.f};
    int c0 = wid * 32 + lr, c1 = wid * 32 + 16 + lr;
    #pragma unroll
    for (int ks = 0; ks < 2; ++ks) {
      int k0 = ks * 32 + lk;
      bf16x8 a0 = *(const bf16x8*)((char*)wbL + ((lr * 128 + k0 * 2) ^ ((lr & 7) << 4)));
      bf16x8 a1 = *(const bf16x8*)((char*)wbL + (((16 + lr) * 128 + k0 * 2) ^ ((lr & 7) << 4)));
      bf16x8 bb0 = *(const bf16x8*)(bct + c0 * 64 + k0);
      bf16x8 bb1 = *(const bf16x8*)(bct + c1 * 64 + k0);
      s00 = mfma16(a0, bb0, s00); s01 = mfma16(a0, bb1, s01);
      s10 = mfma16(a1, bb0, s10); s11 = mfma16(a1, bb1, s11);
    }
    #pragma unroll
    for (int j = 0; j < 4; ++j) {
      sbOut[(tb + lj4 + j) * 128 + c0] = s00[j];
      sbOut[(tb + lj4 + j) * 128 + c1] = s01[j];
      sbOut[(tb + 16 + lj4 + j) * 128 + c0] = s10[j];
      sbOut[(tb + 16 + lj4 + j) * 128 + c1] = s11[j];
    }
  }
  if (tid < 32) {
    float s = vpL[tid * 4 + 0] + vpL[tid * 4 + 1] + vpL[tid * 4 + 2] + vpL[tid * 4 + 3];
    out[VP_OFF + tb + tid] = s;
  }
}

// ---------------------------------------------------------------- kernel C
// Barrier-free: B-frags direct from L2; depth-3 register pipeline (4 rotating buffers).
__device__ __forceinline__ void loadF(bf16x8 (&F)[4], const char* bbase, int m) {
  const char* p = bbase + m * 32768;
  F[0] = *(const bf16x8*)(p);
  F[1] = *(const bf16x8*)(p + 8192);
  F[2] = *(const bf16x8*)(p + 16384);
  F[3] = *(const bf16x8*)(p + 24576);
}

template<int J>
__device__ __forceinline__ void computeT(const bf16x8 (&F)[4], const f32x4 (&wc)[16],
                                         const bf16x8 (&aX)[4][4], f32x4 (&acc)[4]) {
  #pragma unroll
  for (int rg = 0; rg < 4; ++rg) {
    f32x4 y = {0.f, 0.f, 0.f, 0.f};
    #pragma unroll
    for (int ks = 0; ks < 4; ++ks) y = mfma16(aX[rg][ks], F[ks], y);
    #pragma unroll
    for (int jj = 0; jj < 4; ++jj)
      acc[rg][jj] += wc[rg * 4 + jj][J] * y[jj];
  }
}

__global__ __launch_bounds__(256, 1) void kmech(
    const float* __restrict__ x, char* __restrict__ ws)
{
  __shared__ float wL[64 * 64];  // [tok][m]
  const int tid = threadIdx.x;
  const int lane = tid & 63, wid = tid >> 6;
  const int tb = (blockIdx.x >> 1) * 64;
  const int eh = blockIdx.x & 1;
  const int lr = lane & 15, lg = lane >> 4;
  const int lj4 = lg * 4;
  const int wcol = wid * 16;

  const char* wttc = (const char*)(ws + WS_WTT);
  const float* wIn  = (const float*)(ws + WS_W);
  const float* sbIn = (const float*)(ws + WS_SBIAS);
  float* selOut = (float*)(ws + WS_SEL);

  {  // w tile, coalesced
    const float4* s = (const float4*)(wIn + tb * 64);
    float4* d = (float4*)wL;
    #pragma unroll
    for (int i = 0; i < 4; ++i) d[tid + i * 256] = s[tid + i * 256];
  }
  bf16x8 aX[4][4];
  #pragma unroll
  for (int rg = 0; rg < 4; ++rg) {
    const float* xr = x + (tb + rg * 16 + lr) * 128;
    #pragma unroll
    for (int ks = 0; ks < 4; ++ks)
      aX[rg][ks] = cvt8(*(const float4*)(xr + ks * 32 + lg * 8),
                        *(const float4*)(xr + ks * 32 + lg * 8 + 4));
  }
  f32x4 acc[4];
  #pragma unroll
  for (int rg = 0; rg < 4; ++rg) {
    f32x4 a;
    #pragma unroll
    for (int j = 0; j < 4; ++j)
      a[j] = sbIn[(tb + rg * 16 + lj4 + j) * 128 + eh * 64 + wcol + lr];
    acc[rg] = a;
  }
  __syncthreads();

  // per-lane B base: elem = m*16384 + ks*4096 + e*32 + lg*8  (bytes x2)
  const char* bbase = wttc + (size_t)(((eh * 64 + wcol + lr) * 32 + lg * 8) * 2);

  bf16x8 F0[4], F1[4], F2[4], F3[4];
  loadF(F0, bbase, 0);
  loadF(F1, bbase, 1);
  loadF(F2, bbase, 2);

  for (int it = 0; it < 16; ++it) {
    const int base = it * 4;
    f32x4 wc[16];
    #pragma unroll
    for (int rg = 0; rg < 4; ++rg)
      #pragma unroll
      for (int jj = 0; jj < 4; ++jj)
        wc[rg * 4 + jj] = *(const f32x4*)(&wL[(rg * 16 + lj4 + jj) * 64 + base]);
    int n3 = base + 3;
    int n4 = base + 4 > 63 ? 63 : base + 4;
    int n5 = base + 5 > 63 ? 63 : base + 5;
    int n6 = base + 6 > 63 ? 63 : base + 6;
    loadF(F3, bbase, n3);
    computeT<0>(F0, wc, aX, acc);
    loadF(F0, bbase, n4);
    computeT<1>(F1, wc, aX, acc);
    loadF(F1, bbase, n5);
    computeT<2>(F2, wc, aX, acc);
    loadF(F2, bbase, n6);
    computeT<3>(F3, wc, aX, acc);
  }

  #pragma unroll
  for (int rg = 0; rg < 4; ++rg)
    #pragma unroll
    for (int j = 0; j < 4; ++j)
      selOut[(tb + rg * 16 + lj4 + j) * 128 + eh * 64 + wcol + lr] = acc[rg][j];
}

// ---------------------------------------------------------------- kernel D
__global__ __launch_bounds__(256) void kinteg(
    const float* __restrict__ x, const float* __restrict__ bi,
    const char* __restrict__ ws, float* __restrict__ out)
{
  const int tid = threadIdx.x;
  const int lane = tid & 63, wid = tid >> 6;
  const int tb = blockIdx.x * 32;
  const int lr = lane & 15, lk = (lane >> 4) * 8, lj4 = (lane >> 4) * 4;
  const bf16_t* Wit = (const bf16_t*)(ws + WS_WIT);
  const float* sel = (const float*)(ws + WS_SEL);

  bf16x8 aF[2][8];
  #pragma unroll
  for (int rg = 0; rg < 2; ++rg) {
    int t = tb + rg * 16 + lr;
    #pragma unroll
    for (int ks = 0; ks < 8; ++ks) {
      const float* src = (ks < 4) ? (x + t * 128 + ks * 32 + lk)
                                  : (sel + t * 128 + (ks - 4) * 32 + lk);
      aF[rg][ks] = cvt8(*(const float4*)src, *(const float4*)(src + 4));
    }
  }
  #pragma unroll
  for (int cg = 0; cg < 2; ++cg) {
    int c = wid * 32 + cg * 16 + lr;
    f32x4 a0 = {0.f,0.f,0.f,0.f}, a1 = {0.f,0.f,0.f,0.f};
    #pragma unroll
    for (int ks = 0; ks < 8; ++ks) {
      bf16x8 b = *(const bf16x8*)(Wit + c * 256 + ks * 32 + lk);
      a0 = mfma16(aF[0][ks], b, a0);
      a1 = mfma16(aF[1][ks], b, a1);
    }
    float bb = bi[c];
    #pragma unroll
    for (int j = 0; j < 4; ++j) {
      out[(tb + lj4 + j) * 128 + c] = a0[j] + bb;
      out[(tb + 16 + lj4 + j) * 128 + c] = a1[j] + bb;
    }
  }
}

// ---------------------------------------------------------------- launch
extern "C" void kernel_launch(void* const* d_in, const int* in_sizes, int n_in,
                              void* d_out, int out_size, void* d_ws, size_t ws_size,
                              hipStream_t stream)
{
  (void)in_sizes; (void)n_in; (void)out_size; (void)ws_size;
  const float* x   = (const float*)d_in[0];
  const float* ctx = (const float*)d_in[1];
  const float* Wt  = (const float*)d_in[2];
  const float* bt  = (const float*)d_in[3];
  const float* ch  = (const float*)d_in[4];
  const float* Wg  = (const float*)d_in[5];
  const float* bg  = (const float*)d_in[6];
  const float* Wv  = (const float*)d_in[7];
  const float* bv  = (const float*)d_in[8];
  const float* O   = (const float*)d_in[9];
  const float* W1  = (const float*)d_in[10];
  const float* b1  = (const float*)d_in[11];
  const float* W2  = (const float*)d_in[12];
  const float* b2  = (const float*)d_in[13];
  const float* Wi  = (const float*)d_in[14];
  const float* bi  = (const float*)d_in[15];
  float* out = (float*)d_out;
  char* ws = (char*)d_ws;

  kprep<<<153, 256, 0, stream>>>(Wt, bt, ch, Wg, Wv, bv, O, W1, W2, Wi, ws);
  kselect<<<256, 256, 0, stream>>>(x, ctx, b1, b2, bg, ws, out);
  kmech<<<256, 256, 0, stream>>>(x, ws);
  kinteg<<<256, 256, 0, stream>>>(x, bi, ws, out);
}